// Round 1
// baseline (1393.679 us; speedup 1.0000x reference)
//
#include <hip/hip_runtime.h>
#include <math.h>

// ---------------------------------------------------------------------------
// VQ-VAE 3D forward: conv(1->16)->conv(16->32)->conv(32->64)=z_e -> VQ ->
// convT(64->32)->convT(32->16)->convT(16->1)+sigmoid
// All k=4, s=2, p=1. fp32 throughout (no fp32 MFMA on CDNA4; VALU path).
// ---------------------------------------------------------------------------

// ---------------- forward conv (k=4,s=2,p=1), fused bias + optional ReLU ----
// x: [4,CIN,DIN^3], wg: [COUT,CIN,64] (OIDHW), out: [4,COUT,DOUT^3]
// thread = one output spatial position, OCG output channels (grid.y groups).
template<int CIN, int COUT, int DIN, int DOUT, int OCG, int CCH, bool RELU>
__global__ __launch_bounds__(256) void k_conv(const float* __restrict__ x,
                                              const float* __restrict__ wg,
                                              const float* __restrict__ bias,
                                              float* __restrict__ out) {
  __shared__ float wl[CCH * OCG * 64];
  const int tid = threadIdx.x;
  const int g = blockIdx.x * 256 + tid;
  const int ow = g % DOUT;
  int t1 = g / DOUT;
  const int oh = t1 % DOUT; t1 /= DOUT;
  const int od = t1 % DOUT;
  const int b  = t1 / DOUT;
  const int oc0 = blockIdx.y * OCG;

  float acc[OCG];
#pragma unroll
  for (int c = 0; c < OCG; ++c) acc[c] = bias[oc0 + c];

  const int id0 = od * 2 - 1, ih0 = oh * 2 - 1, iw0 = ow * 2 - 1;

#pragma unroll 1
  for (int cc = 0; cc < CIN; cc += CCH) {
    __syncthreads();
    for (int i = tid; i < CCH * OCG * 64; i += 256) {
      const int ci = i / (OCG * 64);
      const int r  = i % (OCG * 64);
      const int oc = r >> 6;
      const int t  = r & 63;
      wl[i] = wg[((size_t)(oc0 + oc) * CIN + (cc + ci)) * 64 + t];
    }
    __syncthreads();
#pragma unroll 1
    for (int ci = 0; ci < CCH; ++ci) {
      const float* xb = x + (size_t)(b * CIN + cc + ci) * (DIN * DIN * DIN);
      const float* wb = wl + ci * (OCG * 64);
#pragma unroll 1
      for (int kd = 0; kd < 4; ++kd) {
        const int id = id0 + kd;
        const bool vd = (unsigned)id < (unsigned)DIN;
#pragma unroll 1
        for (int kh = 0; kh < 4; ++kh) {
          const int ih = ih0 + kh;
          const bool vh = vd && ((unsigned)ih < (unsigned)DIN);
          const float* xr = xb + ((id * DIN + ih) * DIN + iw0);
          const int tb = (kd * 4 + kh) * 4;
#pragma unroll
          for (int kw = 0; kw < 4; ++kw) {
            const bool v = vh && ((unsigned)(iw0 + kw) < (unsigned)DIN);
            const float xv = v ? xr[kw] : 0.0f;
#pragma unroll
            for (int c = 0; c < OCG; ++c)
              acc[c] = fmaf(xv, wb[c * 64 + tb + kw], acc[c]);
          }
        }
      }
    }
  }

  const size_t pstride = (size_t)DOUT * DOUT * DOUT;
  float* ob = out + (size_t)(b * COUT + oc0) * pstride
                  + ((od * DOUT + oh) * DOUT + ow);
#pragma unroll
  for (int c = 0; c < OCG; ++c) {
    float v = acc[c];
    if (RELU) v = fmaxf(v, 0.0f);
    ob[(size_t)c * pstride] = v;
  }
}

// ---------------- transposed conv (k=4,s=2,p=1), gather form ----------------
// x: [4,CIN,DIN^3], wg: [CIN,COUT,64] (PyTorch ConvTranspose layout),
// out: [4,COUT,(2*DIN)^3].  Per output dim o: even -> (i=m-1,k=3),(i=m,k=1);
// odd -> (i=m,k=2),(i=m+1,k=0), m=o>>1.
template<int CIN, int COUT, int DIN, int OCG, int CCH, bool RELU>
__global__ __launch_bounds__(256) void k_convt(const float* __restrict__ x,
                                               const float* __restrict__ wg,
                                               const float* __restrict__ bias,
                                               float* __restrict__ out) {
  constexpr int DOUT = DIN * 2;
  __shared__ float wl[CCH * OCG * 64];
  const int tid = threadIdx.x;
  const int g = blockIdx.x * 256 + tid;
  const int ow = g % DOUT;
  int t1 = g / DOUT;
  const int oh = t1 % DOUT; t1 /= DOUT;
  const int od = t1 % DOUT;
  const int b  = t1 / DOUT;
  const int oc0 = blockIdx.y * OCG;

  int idx_[2], kdx_[2]; bool vdx_[2];
  int ihx_[2], khx_[2]; bool vhx_[2];
  int iwx_[2], kwx_[2]; bool vwx_[2];
  {
    int m = od >> 1;
    if (od & 1) { idx_[0]=m;   kdx_[0]=2; vdx_[0]=true;   idx_[1]=m+1; kdx_[1]=0; vdx_[1]=(m+1<DIN); }
    else        { idx_[0]=m-1; kdx_[0]=3; vdx_[0]=(m>=1); idx_[1]=m;   kdx_[1]=1; vdx_[1]=true; }
    m = oh >> 1;
    if (oh & 1) { ihx_[0]=m;   khx_[0]=2; vhx_[0]=true;   ihx_[1]=m+1; khx_[1]=0; vhx_[1]=(m+1<DIN); }
    else        { ihx_[0]=m-1; khx_[0]=3; vhx_[0]=(m>=1); ihx_[1]=m;   khx_[1]=1; vhx_[1]=true; }
    m = ow >> 1;
    if (ow & 1) { iwx_[0]=m;   kwx_[0]=2; vwx_[0]=true;   iwx_[1]=m+1; kwx_[1]=0; vwx_[1]=(m+1<DIN); }
    else        { iwx_[0]=m-1; kwx_[0]=3; vwx_[0]=(m>=1); iwx_[1]=m;   kwx_[1]=1; vwx_[1]=true; }
  }

  float acc[OCG];
#pragma unroll
  for (int c = 0; c < OCG; ++c) acc[c] = bias[oc0 + c];

#pragma unroll 1
  for (int cc = 0; cc < CIN; cc += CCH) {
    __syncthreads();
    for (int i = tid; i < CCH * OCG * 64; i += 256) {
      const int ci = i / (OCG * 64);
      const int r  = i % (OCG * 64);
      const int oc = r >> 6;
      const int t  = r & 63;
      wl[i] = wg[((size_t)(cc + ci) * COUT + (oc0 + oc)) * 64 + t];
    }
    __syncthreads();
#pragma unroll 1
    for (int ci = 0; ci < CCH; ++ci) {
      const float* xb = x + (size_t)(b * CIN + cc + ci) * (DIN * DIN * DIN);
      const float* wb = wl + ci * (OCG * 64);
#pragma unroll
      for (int a = 0; a < 2; ++a)
#pragma unroll
      for (int e = 0; e < 2; ++e)
#pragma unroll
      for (int f = 0; f < 2; ++f) {
        const bool v = vdx_[a] && vhx_[e] && vwx_[f];
        const float xv = v ? xb[(idx_[a] * DIN + ihx_[e]) * DIN + iwx_[f]] : 0.0f;
        const int t = (kdx_[a] * 4 + khx_[e]) * 4 + kwx_[f];
#pragma unroll
        for (int c = 0; c < OCG; ++c)
          acc[c] = fmaf(xv, wb[c * 64 + t], acc[c]);
      }
    }
  }

  const size_t pstride = (size_t)DOUT * DOUT * DOUT;
  float* ob = out + (size_t)(b * COUT + oc0) * pstride
                  + ((od * DOUT + oh) * DOUT + ow);
#pragma unroll
  for (int c = 0; c < OCG; ++c) {
    float v = acc[c];
    if (RELU) v = fmaxf(v, 0.0f);
    ob[(size_t)c * pstride] = v;
  }
}

// ---------------- VQ: argmin over 512 codes, gather codebook ----------------
// ze: [4,64,4096], cb: [512,64], quant: [4,64,4096].
// One wave per position; codebook staged in 64-code LDS chunks (pad 65).
__global__ __launch_bounds__(256) void k_vq(const float* __restrict__ ze,
                                            const float* __restrict__ cb,
                                            float* __restrict__ quant) {
  __shared__ float ct[64 * 65];
  __shared__ float zs[4][64];
  __shared__ int   bis[4];
  const int tid  = threadIdx.x;
  const int lane = tid & 63;
  const int wv   = tid >> 6;
  const int p0 = blockIdx.x * 4;           // 4 consecutive positions per block
  const int b  = p0 >> 12;
  const int n0 = p0 & 4095;

  {  // coalesced load of the 4 z-vectors (16B chunks), transpose via LDS
    const int c = tid >> 2, j = tid & 3;
    zs[j][c] = ze[((size_t)(b * 64 + c) << 12) + n0 + j];
  }

  float best = 3.4e38f;
  int bi = 0;
#pragma unroll 1
  for (int ch = 0; ch < 8; ++ch) {
    __syncthreads();
    for (int i = tid; i < 4096; i += 256) {
      const int r = i >> 6, c = i & 63;
      ct[r * 65 + c] = cb[((ch * 64 + r) << 6) + c];
    }
    __syncthreads();
    float d = 0.0f;
#pragma unroll 8
    for (int c = 0; c < 64; ++c) {
      const float t = zs[wv][c] - ct[lane * 65 + c];
      d = fmaf(t, t, d);
    }
    const int k = ch * 64 + lane;
    if (d < best) { best = d; bi = k; }   // strict < keeps first occurrence
  }
  // wave argmin with first-index tie-break (jnp.argmin semantics)
#pragma unroll
  for (int off = 32; off > 0; off >>= 1) {
    const float ob = __shfl_down(best, off);
    const int   oi = __shfl_down(bi, off);
    if (ob < best || (ob == best && oi < bi)) { best = ob; bi = oi; }
  }
  if (lane == 0) bis[wv] = bi;
  __syncthreads();
  {  // coalesced gather-write of quantized
    const int c = tid >> 2, j = tid & 3;
    quant[((size_t)(b * 64 + c) << 12) + n0 + j] = cb[(bis[j] << 6) + c];
  }
}

// ---------------- convT3 (16->1) with LDS input tile + sigmoid --------------
// x: [4,16,64^3], wg: [16,1,64], out: [4,1,128^3].
// Block: 8x8x8 output tile; input tile 6^3 per ci; thread -> 2 outputs (oz, oz+4)
// sharing weight regs (same parities).
__global__ __launch_bounds__(256) void k_convt3(const float* __restrict__ x,
                                                const float* __restrict__ wg,
                                                const float* __restrict__ bias,
                                                float* __restrict__ out) {
  __shared__ float xt[16 * 216];   // [ci][lz][ly][lx], 6*6*6
  __shared__ float wl[16 * 64];
  const int tid = threadIdx.x;
  const int bid = blockIdx.x;      // 16*16*16*4
  const int bx = bid & 15, by = (bid >> 4) & 15, bz = (bid >> 8) & 15, b = bid >> 12;
  const int ix0 = bx * 4 - 1, iy0 = by * 4 - 1, iz0 = bz * 4 - 1;

  for (int i = tid; i < 1024; i += 256) wl[i] = wg[i];
  for (int i = tid; i < 16 * 216; i += 256) {
    const int ci = i / 216;
    const int r  = i % 216;
    const int lz = r / 36, ry = r % 36, ly = ry / 6, lx = ry % 6;
    const int iz = iz0 + lz, iy = iy0 + ly, ix = ix0 + lx;
    float v = 0.0f;
    if ((unsigned)iz < 64u && (unsigned)iy < 64u && (unsigned)ix < 64u)
      v = x[(size_t)(b * 16 + ci) * 262144 + ((iz * 64 + iy) * 64 + ix)];
    xt[i] = v;
  }
  __syncthreads();

  const float bv = bias[0];
  const int ox = tid & 7, oy = (tid >> 3) & 7, ozA = tid >> 6;   // ozA in [0,4)
  const int px = ox & 1, py = oy & 1, pz = ozA & 1;
  const int lx0 = (ox >> 1) + px, ly0 = (oy >> 1) + py, lzA = (ozA >> 1) + pz;
  const int kx0 = 3 - px, kx1 = 1 - px;
  const int ky0 = 3 - py, ky1 = 1 - py;
  const int kz0 = 3 - pz, kz1 = 1 - pz;

  float accA = bv, accB = bv;
#pragma unroll 1
  for (int ci = 0; ci < 16; ++ci) {
    const float* xc = xt + ci * 216;
    const float* wc = wl + (ci << 6);
#pragma unroll
    for (int az = 0; az < 2; ++az) {
      const int kz = az ? kz1 : kz0;
      const int lza = lzA + az, lzb = lza + 2;
#pragma unroll
      for (int ay = 0; ay < 2; ++ay) {
        const int ky = ay ? ky1 : ky0;
        const int ly = ly0 + ay;
        const float* wr = wc + ((kz * 4 + ky) << 2);
        const float w0 = wr[kx0], w1 = wr[kx1];
        const float* xa  = xc + (lza * 6 + ly) * 6 + lx0;
        const float* xb2 = xc + (lzb * 6 + ly) * 6 + lx0;
        accA = fmaf(xa[0],  w0, accA);
        accA = fmaf(xa[1],  w1, accA);
        accB = fmaf(xb2[0], w0, accB);
        accB = fmaf(xb2[1], w1, accB);
      }
    }
  }
  const int gx = bx * 8 + ox, gy = by * 8 + oy;
  const size_t base = (size_t)b * 2097152;
  const float sA = 1.0f / (1.0f + expf(-accA));
  const float sB = 1.0f / (1.0f + expf(-accB));
  out[base + ((size_t)((bz * 8 + ozA)     * 128 + gy) * 128) + gx] = sA;
  out[base + ((size_t)((bz * 8 + ozA + 4) * 128 + gy) * 128) + gx] = sB;
}

// ---------------------------------------------------------------------------
extern "C" void kernel_launch(void* const* d_in, const int* in_sizes, int n_in,
                              void* d_out, int out_size, void* d_ws, size_t ws_size,
                              hipStream_t stream) {
  const float* x   = (const float*)d_in[0];
  const float* w1  = (const float*)d_in[1];
  const float* b1  = (const float*)d_in[2];
  const float* w2  = (const float*)d_in[3];
  const float* b2  = (const float*)d_in[4];
  const float* w3  = (const float*)d_in[5];
  const float* b3  = (const float*)d_in[6];
  const float* cb  = (const float*)d_in[7];
  const float* dw1 = (const float*)d_in[8];
  const float* db1 = (const float*)d_in[9];
  const float* dw2 = (const float*)d_in[10];
  const float* db2 = (const float*)d_in[11];
  const float* dw3 = (const float*)d_in[12];
  const float* db3 = (const float*)d_in[13];

  float* outf  = (float*)d_out;
  float* xhat  = outf;               // [4,1,128^3]    8,388,608
  float* quant = outf + 8388608;     // [4,64,16^3]    1,048,576
  float* ze    = outf + 9437184;     // [4,64,16^3]    1,048,576

  // workspace: bufA 16,777,216 floats (64 MiB): y1 then d2
  //            bufB  4,194,304 floats (16 MiB): y2 then d1   (total 80 MiB)
  float* bufA = (float*)d_ws;
  float* bufB = bufA + 16777216;

  // encoder
  k_conv<1, 16, 128, 64, 16, 1, true><<<dim3(4096, 1), 256, 0, stream>>>(x, w1, b1, bufA);
  k_conv<16, 32, 64, 32, 32, 2, true><<<dim3(512, 1), 256, 0, stream>>>(bufA, w2, b2, bufB);
  k_conv<32, 64, 32, 16, 8, 8, false><<<dim3(64, 8), 256, 0, stream>>>(bufB, w3, b3, ze);
  // vector quantization
  k_vq<<<4096, 256, 0, stream>>>(ze, cb, quant);
  // decoder
  k_convt<64, 32, 16, 32, 4, true><<<dim3(512, 1), 256, 0, stream>>>(quant, dw1, db1, bufB);
  k_convt<32, 16, 32, 16, 4, true><<<dim3(4096, 1), 256, 0, stream>>>(bufB, dw2, db2, bufA);
  k_convt3<<<16384, 256, 0, stream>>>(bufA, dw3, db3, xhat);
}